// Round 5
// baseline (1136.566 us; speedup 1.0000x reference)
//
#include <hip/hip_runtime.h>
#include <stdint.h>

#define NB 8
#define NSEQ 4096
#define DMODEL 1024
#define NH 16
#define HDIM 64
#define MROWS (NB*NSEQ)      // 32768
#define NCHUNK 64
#define CHUNKL (NSEQ/NCHUNK) // 64

typedef unsigned short u16;
typedef float f32x4 __attribute__((ext_vector_type(4)));
typedef short bf16x8 __attribute__((ext_vector_type(8)));

__device__ __forceinline__ u16 f2b(float f) {
  unsigned int u = __builtin_bit_cast(unsigned int, f);
  u = (u + 0x7FFFu + ((u >> 16) & 1u)) >> 16;
  return (u16)u;
}
__device__ __forceinline__ float b2f(u16 s) {
  unsigned int u = ((unsigned int)s) << 16;
  return __builtin_bit_cast(float, u);
}

// async global->LDS, 16B per lane (dest = wave-uniform base + lane*16)
__device__ __forceinline__ void gload16(const void* g, void* l) {
  __builtin_amdgcn_global_load_lds(
      (const __attribute__((address_space(1))) void*)g,
      (__attribute__((address_space(3))) void*)l, 16, 0, 0);
}

// ---------------- fused weight fp32 -> bf16 conversion (5 matrices) ----------------
__global__ __launch_bounds__(256) void cvt5(
    const float* __restrict__ a0, const float* __restrict__ a1,
    const float* __restrict__ a2, const float* __restrict__ a3,
    const float* __restrict__ a4,
    u16* __restrict__ b0, u16* __restrict__ b1, u16* __restrict__ b2,
    u16* __restrict__ b3, u16* __restrict__ b4)
{
  const int mat = blockIdx.x >> 7;    // 128 blocks per 1M-elem matrix
  const int blk = blockIdx.x & 127;
  const float* s; u16* d;
  switch (mat) {
    case 0: s = a0; d = b0; break;
    case 1: s = a1; d = b1; break;
    case 2: s = a2; d = b2; break;
    case 3: s = a3; d = b3; break;
    default: s = a4; d = b4; break;
  }
#pragma unroll
  for (int it = 0; it < 8; ++it) {
    const int idx = blk*8192 + it*1024 + threadIdx.x*4;
    const float4 v = *(const float4*)(s + idx);
    ushort4 o; o.x = f2b(v.x); o.y = f2b(v.y); o.z = f2b(v.z); o.w = f2b(v.w);
    *(ushort4*)(d + idx) = o;
  }
}

// ---------------- mix: A_p[row,k] = m_p[k]*x[row,k] + (1-m_p[k])*x[rowm1,k], 4 projections ----------------
// 16 elements per thread for MLP; 8192 blocks.
__global__ __launch_bounds__(256) void mix4_kernel(
    const float* __restrict__ X,
    const float* __restrict__ mg, const float* __restrict__ mr,
    const float* __restrict__ mk, const float* __restrict__ mv,
    u16* __restrict__ Ag, u16* __restrict__ Ar, u16* __restrict__ Ak, u16* __restrict__ Av)
{
  const int i = blockIdx.x*256 + threadIdx.x;   // one thread = 16 elements
  const int row = i >> 6;                        // 64 threads per 1024-col row
  const int c16 = (i & 63) << 4;
  const int nidx = row & (NSEQ-1);
  const int rowm1 = (nidx == 0) ? row + (NSEQ-1) : row - 1;  // roll within batch
  const size_t xo = (size_t)row*DMODEL + c16;
  const size_t so = (size_t)rowm1*DMODEL + c16;
  float xv[16], sv[16], mm[16];
#pragma unroll
  for (int q = 0; q < 4; ++q) {
    *(float4*)&xv[q*4] = *(const float4*)(X + xo + q*4);
    *(float4*)&sv[q*4] = *(const float4*)(X + so + q*4);
  }

#define DO_MIX(MP, AP) { \
    _Pragma("unroll") \
    for (int q = 0; q < 4; ++q) *(float4*)&mm[q*4] = *(const float4*)(MP + c16 + q*4); \
    bf16x8 o0, o1; \
    _Pragma("unroll") \
    for (int j = 0; j < 8; ++j) o0[j] = (short)f2b(mm[j]*xv[j] + (1.f-mm[j])*sv[j]); \
    _Pragma("unroll") \
    for (int j = 0; j < 8; ++j) o1[j] = (short)f2b(mm[8+j]*xv[8+j] + (1.f-mm[8+j])*sv[8+j]); \
    *(bf16x8*)(AP + xo) = o0; \
    *(bf16x8*)(AP + xo + 8) = o1; }

  DO_MIX(mg, Ag)
  DO_MIX(mr, Ar)
  DO_MIX(mk, Ak)
  DO_MIX(mv, Av)
#undef DO_MIX
}

// ---------------- GEMM 256x256 8-phase (T1+T2+T3+T4+T5), C = A @ W^T + b ----------------
#define FENCE asm volatile("" ::: "memory")
#define BAR() { FENCE; __builtin_amdgcn_s_barrier(); FENCE; }
#define PRIO1 __builtin_amdgcn_s_setprio(1)
#define PRIO0 __builtin_amdgcn_s_setprio(0)
#define VM6 asm volatile("s_waitcnt vmcnt(6)" ::: "memory")
#define VM4 asm volatile("s_waitcnt vmcnt(4)" ::: "memory")
#define VM0 asm volatile("s_waitcnt vmcnt(0)" ::: "memory")

template<int OUTBF>
__global__ __launch_bounds__(512, 2) void gemm256(
    const u16* __restrict__ Abf, const u16* __restrict__ Wb,
    const float* __restrict__ bias, float* __restrict__ outF, u16* __restrict__ outB)
{
  __shared__ __align__(16) char lds[131072];
  const int tid = threadIdx.x;
  const int wave = tid >> 6, lane = tid & 63;
  const int wm = wave >> 2, wn = wave & 3;       // 2 x 4 waves
  const int rla = lane & 15, kgrp = lane >> 4;

  // T1: XCD-bijective swizzle. 512 blocks, xcd = wgid&7 owns by in [16*xcd, 16*xcd+16)
  const int wg = blockIdx.x;
  const int xcd = wg & 7, slot = wg >> 3;
  const int by = xcd*16 + (slot >> 2);
  const int bx = slot & 3;

  // staging source offsets (pre-swizzled): F = (wave*2+i)*1024 + lane*16
  const int F0 = (wave*2+0)*1024 + lane*16;
  const int F1 = (wave*2+1)*1024 + lane*16;
  const int r0 = F0 >> 6, r1 = F1 >> 6;
  const int c80 = ((F0 >> 4) & 3) ^ ((r0 >> 1) & 3);
  const int c81 = ((F1 >> 4) & 3) ^ ((r1 >> 1) & 3);
  const char* Ab = (const char*)Abf;
  const char* Bbp = (const char*)Wb;
  const unsigned ga0 = (unsigned)by*256*2048 + r0*2048 + c80*16;
  const unsigned ga1 = (unsigned)by*256*2048 + r1*2048 + c81*16;
  const unsigned gb0 = (unsigned)bx*256*2048 + r0*2048 + c80*16;
  const unsigned gb1 = (unsigned)bx*256*2048 + r1*2048 + c81*16;
  const int dst0 = wave*2048;
  const int dst1 = wave*2048 + 1024;

  f32x4 acc[8][4];
#pragma unroll
  for (int i = 0; i < 8; ++i)
#pragma unroll
    for (int j = 0; j < 4; ++j) acc[i][j] = f32x4{0.f,0.f,0.f,0.f};
  bf16x8 af[8], bfr[4];
  const int lane_ds = rla*64 + ((kgrp ^ ((rla>>1)&3)) << 4);

#define LDS_A(D,KK) (lds + (D)*32768 + (KK)*16384)
#define LDS_B(D,KK) (lds + 65536 + (D)*32768 + (KK)*16384)
#define LDA(D,KK) { _Pragma("unroll") for (int mi_ = 0; mi_ < 8; ++mi_) \
    af[mi_] = *(const bf16x8*)(LDS_A(D,KK) + (wm*128 + mi_*16)*64 + lane_ds); }
#define LDB(P,D,KK) { _Pragma("unroll") for (int j_ = 0; j_ < 2; ++j_) \
    bfr[(P)*2+j_] = *(const bf16x8*)(LDS_B(D,KK) + (wn*64 + ((P)*2+j_)*16)*64 + lane_ds); }
#define MM(P) { _Pragma("unroll") for (int mi_ = 0; mi_ < 8; ++mi_) { \
    acc[mi_][(P)*2+0] = __builtin_amdgcn_mfma_f32_16x16x32_bf16(af[mi_], bfr[(P)*2+0], acc[mi_][(P)*2+0], 0,0,0); \
    acc[mi_][(P)*2+1] = __builtin_amdgcn_mfma_f32_16x16x32_bf16(af[mi_], bfr[(P)*2+1], acc[mi_][(P)*2+1], 0,0,0); } }
#define STAGE(ISB, T, KK) { \
    const char* g_ = (ISB) ? Bbp : Ab; \
    const unsigned o0_ = ((ISB) ? gb0 : ga0) + (T)*128 + (KK)*64; \
    const unsigned o1_ = ((ISB) ? gb1 : ga1) + (T)*128 + (KK)*64; \
    char* l_ = (ISB) ? LDS_B((T)&1, KK) : LDS_A((T)&1, KK); \
    gload16(g_ + o0_, l_ + dst0); \
    gload16(g_ + o1_, l_ + dst1); }

  // prologue: tile0 all 4 halves, then tile1 A0,B0,A1
  STAGE(0, 0, 0); STAGE(1, 0, 0); STAGE(0, 0, 1); STAGE(1, 0, 1);
  VM4;
  STAGE(0, 1, 0); STAGE(1, 1, 0); STAGE(0, 1, 1);
  VM6;
  BAR();

  for (int i = 0; i < 8; ++i) {
    const int t1 = 2*i+1, t2 = 2*i+2, t3 = 2*i+3;
    const bool s2 = (i < 7);
    // ph1: compute tile 2i (buf0) kk0 ni01
    LDA(0,0); LDB(0,0,0); STAGE(1, t1, 1);
    BAR(); PRIO1; MM(0); PRIO0; BAR();
    // ph2: kk0 ni23
    LDB(1,0,0); if (s2) STAGE(0, t2, 0);
    BAR(); PRIO1; MM(1); PRIO0; BAR();
    // ph3: kk1 ni01
    LDA(0,1); LDB(0,0,1); if (s2) STAGE(1, t2, 0);
    BAR(); PRIO1; MM(0); PRIO0; BAR();
    // ph4: kk1 ni23  (+ counted vmcnt guarding tile 2i+1 reads)
    LDB(1,0,1); if (s2) STAGE(0, t2, 1);
    BAR(); PRIO1; MM(1); PRIO0;
    if (i == 7) { VM0; } else { VM6; }
    BAR();
    // ph5: tile 2i+1 (buf1) kk0 ni01
    LDA(1,0); LDB(0,1,0); if (s2) STAGE(1, t2, 1);
    BAR(); PRIO1; MM(0); PRIO0; BAR();
    // ph6
    LDB(1,1,0); if (s2) STAGE(0, t3, 0);
    BAR(); PRIO1; MM(1); PRIO0; BAR();
    // ph7
    LDA(1,1); LDB(0,1,1); if (s2) STAGE(1, t3, 0);
    BAR(); PRIO1; MM(0); PRIO0; BAR();
    // ph8  (+ counted vmcnt guarding next-iter tile reads)
    LDB(1,1,1); if (s2) STAGE(0, t3, 1);
    BAR(); PRIO1; MM(1); PRIO0; VM6; BAR();
  }

  // epilogue: bias + store. C/D: col=lane&15, row=(lane>>4)*4+q
  float bval[4];
#pragma unroll
  for (int ni = 0; ni < 4; ++ni) bval[ni] = bias[bx*256 + wn*64 + ni*16 + rla];
#pragma unroll
  for (int mi = 0; mi < 8; ++mi) {
#pragma unroll
    for (int ni = 0; ni < 4; ++ni) {
      const int gr0 = by*256 + wm*128 + mi*16 + kgrp*4;
      const int gc  = bx*256 + wn*64 + ni*16 + rla;
#pragma unroll
      for (int q = 0; q < 4; ++q) {
        const float v = acc[mi][ni][q] + bval[ni];
        const size_t o = (size_t)(gr0 + q)*DMODEL + gc;
        if (OUTBF) outB[o] = f2b(v);
        else       outF[o] = v;
      }
    }
  }
#undef LDS_A
#undef LDS_B
#undef LDA
#undef LDB
#undef MM
#undef STAGE
}

// ---------------- flag clear (graph-replay safe) ----------------
__global__ void zero_flags(int* flags) { flags[threadIdx.x] = 0; }

// ---------------- fused scan: local scan + aggregate-lookback carry + LN + gate -> h ----------------
// 512 blocks = (b, chunk); 256 thr = 16 heads x 16 lanes, 4 ch/lane.
__global__ __launch_bounds__(256) void scan_fused(
    const u16* __restrict__ kbuf, const u16* __restrict__ vbuf,
    const u16* __restrict__ rbuf, const u16* __restrict__ gbuf,
    u16* __restrict__ hbuf, const float* __restrict__ w,
    const float* __restrict__ u, float* __restrict__ agg, int* __restrict__ flags)
{
  const int c = blockIdx.x & (NCHUNK-1);
  const int b = blockIdx.x >> 6;
  const int hh = threadIdx.x >> 4;
  const int ch0 = (threadIdx.x & 15) << 2;
  const int hch = hh*HDIM + ch0;

  float dd[4], dL[4], uv[4];
#pragma unroll
  for (int j = 0; j < 4; ++j) {
    const float e = expf(w[hch + j]);
    dd[j] = expf(-e);
    dL[j] = expf(-e * (float)CHUNKL);
    uv[j] = u[hch + j];
  }

  const size_t base = ((size_t)b*NSEQ + (size_t)c*CHUNKL)*DMODEL + hch;

  // phase A: local aggregate
  float acc[4] = {0.f, 0.f, 0.f, 0.f};
#pragma unroll 2
  for (int i = 0; i < CHUNKL; ++i) {
    const size_t idx = base + (size_t)i*DMODEL;
    const ushort4 k4 = *(const ushort4*)(kbuf + idx);
    const ushort4 v4 = *(const ushort4*)(vbuf + idx);
    acc[0] = dd[0]*acc[0] + b2f(k4.x)*b2f(v4.x);
    acc[1] = dd[1]*acc[1] + b2f(k4.y)*b2f(v4.y);
    acc[2] = dd[2]*acc[2] + b2f(k4.z)*b2f(v4.z);
    acc[3] = dd[3]*acc[3] + b2f(k4.w)*b2f(v4.w);
  }
  {
    float4 o; o.x = acc[0]; o.y = acc[1]; o.z = acc[2]; o.w = acc[3];
    *(float4*)(agg + (size_t)blockIdx.x*DMODEL + hch) = o;
  }
  __threadfence();     // device-scope: make agg stores visible
  __syncthreads();     // all threads' stores done before flag
  if (threadIdx.x == 0)
    __hip_atomic_store(&flags[blockIdx.x], 1, __ATOMIC_RELEASE, __HIP_MEMORY_SCOPE_AGENT);

  // lookback: carry = sum_{j<c} agg_j * dL^(c-1-j)   (no serial prefix chain)
  float carry[4] = {0.f, 0.f, 0.f, 0.f};
  float wf[4] = {1.f, 1.f, 1.f, 1.f};
  const int b0 = b*NCHUNK;
  for (int j = c-1; j >= 0; --j) {
    while (__hip_atomic_load(&flags[b0 + j], __ATOMIC_ACQUIRE, __HIP_MEMORY_SCOPE_AGENT) == 0)
      __builtin_amdgcn_s_sleep(2);
    const float4 a4 = *(const float4*)(agg + (size_t)(b0 + j)*DMODEL + hch);
    carry[0] += wf[0]*a4.x; carry[1] += wf[1]*a4.y;
    carry[2] += wf[2]*a4.z; carry[3] += wf[3]*a4.w;
    wf[0] *= dL[0]; wf[1] *= dL[1]; wf[2] *= dL[2]; wf[3] *= dL[3];
  }

  // phase B: rescan with carry as initial state; fuse u*kv, r*, LN, gate
  float acc2[4] = {carry[0], carry[1], carry[2], carry[3]};
#pragma unroll 2
  for (int i = 0; i < CHUNKL; ++i) {
    const size_t idx = base + (size_t)i*DMODEL;
    const ushort4 k4 = *(const ushort4*)(kbuf + idx);
    const ushort4 v4 = *(const ushort4*)(vbuf + idx);
    const ushort4 r4 = *(const ushort4*)(rbuf + idx);
    const ushort4 g4 = *(const ushort4*)(gbuf + idx);
    float rw[4];
    float s1 = 0.f, s2 = 0.f;
    {
      const float kv = b2f(k4.x)*b2f(v4.x);
      acc2[0] = dd[0]*acc2[0] + kv;
      rw[0] = b2f(r4.x)*(acc2[0] + uv[0]*kv); s1 += rw[0]; s2 += rw[0]*rw[0];
    }
    {
      const float kv = b2f(k4.y)*b2f(v4.y);
      acc2[1] = dd[1]*acc2[1] + kv;
      rw[1] = b2f(r4.y)*(acc2[1] + uv[1]*kv); s1 += rw[1]; s2 += rw[1]*rw[1];
    }
    {
      const float kv = b2f(k4.z)*b2f(v4.z);
      acc2[2] = dd[2]*acc2[2] + kv;
      rw[2] = b2f(r4.z)*(acc2[2] + uv[2]*kv); s1 += rw[2]; s2 += rw[2]*rw[2];
    }
    {
      const float kv = b2f(k4.w)*b2f(v4.w);
      acc2[3] = dd[3]*acc2[3] + kv;
      rw[3] = b2f(r4.w)*(acc2[3] + uv[3]*kv); s1 += rw[3]; s2 += rw[3]*rw[3];
    }
#pragma unroll
    for (int off = 8; off >= 1; off >>= 1) {
      s1 += __shfl_xor(s1, off);
      s2 += __shfl_xor(s2, off);
    }
    const float mean = s1 * (1.f/64.f);
    const float var = s2 * (1.f/64.f) - mean*mean;
    const float rstd = rsqrtf(var + 1e-5f);
    ushort4 o;
    o.x = f2b((rw[0]-mean)*rstd * (1.f/(1.f+expf(-b2f(g4.x)))));
    o.y = f2b((rw[1]-mean)*rstd * (1.f/(1.f+expf(-b2f(g4.y)))));
    o.z = f2b((rw[2]-mean)*rstd * (1.f/(1.f+expf(-b2f(g4.z)))));
    o.w = f2b((rw[3]-mean)*rstd * (1.f/(1.f+expf(-b2f(g4.w)))));
    *(ushort4*)(hbuf + idx) = o;
  }
}

// ---------------- launch ----------------
extern "C" void kernel_launch(void* const* d_in, const int* in_sizes, int n_in,
                              void* d_out, int out_size, void* d_ws, size_t ws_size,
                              hipStream_t stream)
{
  const float* x   = (const float*)d_in[0];
  const float* WgW = (const float*)d_in[1];
  const float* Wgb = (const float*)d_in[2];
  const float* WrW = (const float*)d_in[3];
  const float* Wrb = (const float*)d_in[4];
  const float* WkW = (const float*)d_in[5];
  const float* Wkb = (const float*)d_in[6];
  const float* WvW = (const float*)d_in[7];
  const float* Wvb = (const float*)d_in[8];
  const float* WoW = (const float*)d_in[9];
  const float* Wob = (const float*)d_in[10];
  const float* mg  = (const float*)d_in[11];
  const float* mr  = (const float*)d_in[12];
  const float* mk  = (const float*)d_in[13];
  const float* mv  = (const float*)d_in[14];
  const float* w   = (const float*)d_in[15];
  const float* u   = (const float*)d_in[16];
  char* ws = (char*)d_ws;

  const size_t WBB = (size_t)DMODEL*DMODEL*2;   // 2 MiB
  u16* WgB = (u16*)(ws + 0*WBB);
  u16* WrB = (u16*)(ws + 1*WBB);
  u16* WkB = (u16*)(ws + 2*WBB);
  u16* WvB = (u16*)(ws + 3*WBB);
  u16* WoB = (u16*)(ws + 4*WBB);
  size_t off = 5*WBB;
  const size_t EL = (size_t)MROWS*DMODEL;       // 33.5M elements

  // Am slots (4 x 64MiB bf16). Consumption order allows aliasing:
  //   kbuf -> Amg slot (free after g GEMM), vbuf -> Amr slot, hbuf -> Amk slot.
  char* amBase = ws + off;
  u16* Amg = (u16*)(amBase);
  u16* Amr = (u16*)(amBase + EL*2);
  u16* Amk = (u16*)(amBase + EL*4);
  u16* Amv = (u16*)(amBase + EL*6);
  u16* kbuf = Amg;
  u16* vbuf = Amr;
  u16* hbuf = Amk;
  off += EL*8;
  u16* gbuf = (u16*)(ws + off);   off += EL*2;
  u16* rbuf = (u16*)(ws + off);   off += EL*2;
  float* agg = (float*)(ws + off); off += (size_t)NB*NCHUNK*DMODEL*4;   // 2 MiB
  int* flags = (int*)(ws + off);   off += (size_t)NB*NCHUNK*4;

  cvt5<<<640, 256, 0, stream>>>(WgW, WrW, WkW, WvW, WoW, WgB, WrB, WkB, WvB, WoB);

  mix4_kernel<<<(int)(EL/16/256), 256, 0, stream>>>(x, mg, mr, mk, mv, Amg, Amr, Amk, Amv);

  gemm256<1><<<512, 512, 0, stream>>>(Amg, WgB, Wgb, nullptr, gbuf);
  gemm256<1><<<512, 512, 0, stream>>>(Amr, WrB, Wrb, nullptr, rbuf);
  gemm256<1><<<512, 512, 0, stream>>>(Amk, WkB, Wkb, nullptr, kbuf);   // kbuf over consumed Amg
  gemm256<1><<<512, 512, 0, stream>>>(Amv, WvB, Wvb, nullptr, vbuf);   // vbuf over consumed Amr

  zero_flags<<<1, NB*NCHUNK, 0, stream>>>(flags);
  scan_fused<<<NB*NCHUNK, 256, 0, stream>>>(kbuf, vbuf, rbuf, gbuf, hbuf, w, u, agg, flags);

  gemm256<0><<<512, 512, 0, stream>>>(hbuf, WoB, Wob, (float*)d_out, nullptr);
}

// Round 6
// 581.501 us; speedup vs baseline: 1.9545x; 1.9545x over previous
//
#include <hip/hip_runtime.h>
#include <stdint.h>

#define NB 8
#define NSEQ 4096
#define DMODEL 1024
#define NH 16
#define HDIM 64
#define MROWS (NB*NSEQ)      // 32768
#define NCHUNK 128
#define CHUNKL (NSEQ/NCHUNK) // 32

typedef unsigned short u16;
typedef float f32x4 __attribute__((ext_vector_type(4)));
typedef short bf16x8 __attribute__((ext_vector_type(8)));

__device__ __forceinline__ u16 f2b(float f) {
  unsigned int u = __builtin_bit_cast(unsigned int, f);
  u = (u + 0x7FFFu + ((u >> 16) & 1u)) >> 16;
  return (u16)u;
}
__device__ __forceinline__ float b2f(u16 s) {
  unsigned int u = ((unsigned int)s) << 16;
  return __builtin_bit_cast(float, u);
}

// async global->LDS, 16B per lane (dest = wave-uniform base + lane*16)
__device__ __forceinline__ void gload16(const void* g, void* l) {
  __builtin_amdgcn_global_load_lds(
      (const __attribute__((address_space(1))) void*)g,
      (__attribute__((address_space(3))) void*)l, 16, 0, 0);
}

// ---------------- fused weight fp32 -> bf16 conversion (5 matrices) ----------------
__global__ __launch_bounds__(256) void cvt5(
    const float* __restrict__ a0, const float* __restrict__ a1,
    const float* __restrict__ a2, const float* __restrict__ a3,
    const float* __restrict__ a4,
    u16* __restrict__ b0, u16* __restrict__ b1, u16* __restrict__ b2,
    u16* __restrict__ b3, u16* __restrict__ b4)
{
  const int mat = blockIdx.x >> 7;    // 128 blocks per 1M-elem matrix
  const int blk = blockIdx.x & 127;
  const float* s; u16* d;
  switch (mat) {
    case 0: s = a0; d = b0; break;
    case 1: s = a1; d = b1; break;
    case 2: s = a2; d = b2; break;
    case 3: s = a3; d = b3; break;
    default: s = a4; d = b4; break;
  }
#pragma unroll
  for (int it = 0; it < 8; ++it) {
    const int idx = blk*8192 + it*1024 + threadIdx.x*4;
    const float4 v = *(const float4*)(s + idx);
    ushort4 o; o.x = f2b(v.x); o.y = f2b(v.y); o.z = f2b(v.z); o.w = f2b(v.w);
    *(ushort4*)(d + idx) = o;
  }
}

// ---------------- mix: A_p[row,k] = m_p[k]*x[row,k] + (1-m_p[k])*x[rowm1,k], 4 projections ----------------
// 16 elements per thread; 8192 blocks.
__global__ __launch_bounds__(256) void mix4_kernel(
    const float* __restrict__ X,
    const float* __restrict__ mg, const float* __restrict__ mr,
    const float* __restrict__ mk, const float* __restrict__ mv,
    u16* __restrict__ Ag, u16* __restrict__ Ar, u16* __restrict__ Ak, u16* __restrict__ Av)
{
  const int i = blockIdx.x*256 + threadIdx.x;   // one thread = 16 elements
  const int row = i >> 6;                        // 64 threads per 1024-col row
  const int c16 = (i & 63) << 4;
  const int nidx = row & (NSEQ-1);
  const int rowm1 = (nidx == 0) ? row + (NSEQ-1) : row - 1;  // roll within batch
  const size_t xo = (size_t)row*DMODEL + c16;
  const size_t so = (size_t)rowm1*DMODEL + c16;
  float xv[16], sv[16], mm[16];
#pragma unroll
  for (int q = 0; q < 4; ++q) {
    *(float4*)&xv[q*4] = *(const float4*)(X + xo + q*4);
    *(float4*)&sv[q*4] = *(const float4*)(X + so + q*4);
  }

#define DO_MIX(MP, AP) { \
    _Pragma("unroll") \
    for (int q = 0; q < 4; ++q) *(float4*)&mm[q*4] = *(const float4*)(MP + c16 + q*4); \
    bf16x8 o0, o1; \
    _Pragma("unroll") \
    for (int j = 0; j < 8; ++j) o0[j] = (short)f2b(mm[j]*xv[j] + (1.f-mm[j])*sv[j]); \
    _Pragma("unroll") \
    for (int j = 0; j < 8; ++j) o1[j] = (short)f2b(mm[8+j]*xv[8+j] + (1.f-mm[8+j])*sv[8+j]); \
    *(bf16x8*)(AP + xo) = o0; \
    *(bf16x8*)(AP + xo + 8) = o1; }

  DO_MIX(mg, Ag)
  DO_MIX(mr, Ar)
  DO_MIX(mk, Ak)
  DO_MIX(mv, Av)
#undef DO_MIX
}

// ---------------- GEMM 256x256 8-phase (T1+T2+T3+T4+T5), C = A @ W^T + b ----------------
#define FENCE asm volatile("" ::: "memory")
#define BAR() { FENCE; __builtin_amdgcn_s_barrier(); FENCE; }
#define PRIO1 __builtin_amdgcn_s_setprio(1)
#define PRIO0 __builtin_amdgcn_s_setprio(0)
#define VM6 asm volatile("s_waitcnt vmcnt(6)" ::: "memory")
#define VM4 asm volatile("s_waitcnt vmcnt(4)" ::: "memory")
#define VM0 asm volatile("s_waitcnt vmcnt(0)" ::: "memory")

template<int OUTBF>
__global__ __launch_bounds__(512, 2) void gemm256(
    const u16* __restrict__ Abf, const u16* __restrict__ Wb,
    const float* __restrict__ bias, float* __restrict__ outF, u16* __restrict__ outB)
{
  __shared__ __align__(16) char lds[131072];
  const int tid = threadIdx.x;
  const int wave = tid >> 6, lane = tid & 63;
  const int wm = wave >> 2, wn = wave & 3;       // 2 x 4 waves
  const int rla = lane & 15, kgrp = lane >> 4;

  // T1: XCD-bijective swizzle. 512 blocks, xcd = wgid&7 owns by in [16*xcd, 16*xcd+16)
  const int wg = blockIdx.x;
  const int xcd = wg & 7, slot = wg >> 3;
  const int by = xcd*16 + (slot >> 2);
  const int bx = slot & 3;

  // staging source offsets (pre-swizzled): F = (wave*2+i)*1024 + lane*16
  const int F0 = (wave*2+0)*1024 + lane*16;
  const int F1 = (wave*2+1)*1024 + lane*16;
  const int r0 = F0 >> 6, r1 = F1 >> 6;
  const int c80 = ((F0 >> 4) & 3) ^ ((r0 >> 1) & 3);
  const int c81 = ((F1 >> 4) & 3) ^ ((r1 >> 1) & 3);
  const char* Ab = (const char*)Abf;
  const char* Bbp = (const char*)Wb;
  const unsigned ga0 = (unsigned)by*256*2048 + r0*2048 + c80*16;
  const unsigned ga1 = (unsigned)by*256*2048 + r1*2048 + c81*16;
  const unsigned gb0 = (unsigned)bx*256*2048 + r0*2048 + c80*16;
  const unsigned gb1 = (unsigned)bx*256*2048 + r1*2048 + c81*16;
  const int dst0 = wave*2048;
  const int dst1 = wave*2048 + 1024;

  f32x4 acc[8][4];
#pragma unroll
  for (int i = 0; i < 8; ++i)
#pragma unroll
    for (int j = 0; j < 4; ++j) acc[i][j] = f32x4{0.f,0.f,0.f,0.f};
  bf16x8 af[8], bfr[4];
  const int lane_ds = rla*64 + ((kgrp ^ ((rla>>1)&3)) << 4);

#define LDS_A(D,KK) (lds + (D)*32768 + (KK)*16384)
#define LDS_B(D,KK) (lds + 65536 + (D)*32768 + (KK)*16384)
#define LDA(D,KK) { _Pragma("unroll") for (int mi_ = 0; mi_ < 8; ++mi_) \
    af[mi_] = *(const bf16x8*)(LDS_A(D,KK) + (wm*128 + mi_*16)*64 + lane_ds); }
#define LDB(P,D,KK) { _Pragma("unroll") for (int j_ = 0; j_ < 2; ++j_) \
    bfr[(P)*2+j_] = *(const bf16x8*)(LDS_B(D,KK) + (wn*64 + ((P)*2+j_)*16)*64 + lane_ds); }
#define MM(P) { _Pragma("unroll") for (int mi_ = 0; mi_ < 8; ++mi_) { \
    acc[mi_][(P)*2+0] = __builtin_amdgcn_mfma_f32_16x16x32_bf16(af[mi_], bfr[(P)*2+0], acc[mi_][(P)*2+0], 0,0,0); \
    acc[mi_][(P)*2+1] = __builtin_amdgcn_mfma_f32_16x16x32_bf16(af[mi_], bfr[(P)*2+1], acc[mi_][(P)*2+1], 0,0,0); } }
#define STAGE(ISB, T, KK) { \
    const char* g_ = (ISB) ? Bbp : Ab; \
    const unsigned o0_ = ((ISB) ? gb0 : ga0) + (T)*128 + (KK)*64; \
    const unsigned o1_ = ((ISB) ? gb1 : ga1) + (T)*128 + (KK)*64; \
    char* l_ = (ISB) ? LDS_B((T)&1, KK) : LDS_A((T)&1, KK); \
    gload16(g_ + o0_, l_ + dst0); \
    gload16(g_ + o1_, l_ + dst1); }

  // prologue: tile0 all 4 halves, then tile1 A0,B0,A1
  STAGE(0, 0, 0); STAGE(1, 0, 0); STAGE(0, 0, 1); STAGE(1, 0, 1);
  VM4;
  STAGE(0, 1, 0); STAGE(1, 1, 0); STAGE(0, 1, 1);
  VM6;
  BAR();

  for (int i = 0; i < 8; ++i) {
    const int t1 = 2*i+1, t2 = 2*i+2, t3 = 2*i+3;
    const bool s2 = (i < 7);
    // ph1: compute tile 2i (buf0) kk0 ni01
    LDA(0,0); LDB(0,0,0); STAGE(1, t1, 1);
    BAR(); PRIO1; MM(0); PRIO0; BAR();
    // ph2: kk0 ni23
    LDB(1,0,0); if (s2) STAGE(0, t2, 0);
    BAR(); PRIO1; MM(1); PRIO0; BAR();
    // ph3: kk1 ni01
    LDA(0,1); LDB(0,0,1); if (s2) STAGE(1, t2, 0);
    BAR(); PRIO1; MM(0); PRIO0; BAR();
    // ph4: kk1 ni23  (+ counted vmcnt guarding tile 2i+1 reads)
    LDB(1,0,1); if (s2) STAGE(0, t2, 1);
    BAR(); PRIO1; MM(1); PRIO0;
    if (i == 7) { VM0; } else { VM6; }
    BAR();
    // ph5: tile 2i+1 (buf1) kk0 ni01
    LDA(1,0); LDB(0,1,0); if (s2) STAGE(1, t2, 1);
    BAR(); PRIO1; MM(0); PRIO0; BAR();
    // ph6
    LDB(1,1,0); if (s2) STAGE(0, t3, 0);
    BAR(); PRIO1; MM(1); PRIO0; BAR();
    // ph7
    LDA(1,1); LDB(0,1,1); if (s2) STAGE(1, t3, 0);
    BAR(); PRIO1; MM(0); PRIO0; BAR();
    // ph8  (+ counted vmcnt guarding next-iter tile reads)
    LDB(1,1,1); if (s2) STAGE(0, t3, 1);
    BAR(); PRIO1; MM(1); PRIO0; VM6; BAR();
  }

  // epilogue: bias + store. C/D: col=lane&15, row=(lane>>4)*4+q
  float bval[4];
#pragma unroll
  for (int ni = 0; ni < 4; ++ni) bval[ni] = bias[bx*256 + wn*64 + ni*16 + rla];
#pragma unroll
  for (int mi = 0; mi < 8; ++mi) {
#pragma unroll
    for (int ni = 0; ni < 4; ++ni) {
      const int gr0 = by*256 + wm*128 + mi*16 + kgrp*4;
      const int gc  = bx*256 + wn*64 + ni*16 + rla;
#pragma unroll
      for (int q = 0; q < 4; ++q) {
        const float v = acc[mi][ni][q] + bval[ni];
        const size_t o = (size_t)(gr0 + q)*DMODEL + gc;
        if (OUTBF) outB[o] = f2b(v);
        else       outF[o] = v;
      }
    }
  }
#undef LDS_A
#undef LDS_B
#undef LDA
#undef LDB
#undef MM
#undef STAGE
}

// ---------------- scan pass 1: chunk-local carry compute only ----------------
// 1024 blocks = (b, chunk); 256 thr = 16 heads x 16 lanes, 4 ch/lane.
__global__ __launch_bounds__(256) void scan_pass1(
    const u16* __restrict__ kbuf, const u16* __restrict__ vbuf,
    const float* __restrict__ w, float* __restrict__ chunkAcc)
{
  const int c = blockIdx.x & (NCHUNK-1);
  const int b = blockIdx.x >> 7;            // NCHUNK=128
  const int hh = threadIdx.x >> 4;          // head 0..15
  const int ch0 = (threadIdx.x & 15) << 2;  // channel base 0..60
  const int hch = hh*HDIM + ch0;

  float dd[4];
#pragma unroll
  for (int j = 0; j < 4; ++j) dd[j] = expf(-expf(w[hch + j]));

  const size_t base = ((size_t)b*NSEQ + (size_t)c*CHUNKL)*DMODEL + hch;
  float acc[4] = {0.f, 0.f, 0.f, 0.f};
#pragma unroll 4
  for (int i = 0; i < CHUNKL; ++i) {
    const size_t idx = base + (size_t)i*DMODEL;
    const ushort4 k4 = *(const ushort4*)(kbuf + idx);
    const ushort4 v4 = *(const ushort4*)(vbuf + idx);
    acc[0] = dd[0]*acc[0] + b2f(k4.x)*b2f(v4.x);
    acc[1] = dd[1]*acc[1] + b2f(k4.y)*b2f(v4.y);
    acc[2] = dd[2]*acc[2] + b2f(k4.z)*b2f(v4.z);
    acc[3] = dd[3]*acc[3] + b2f(k4.w)*b2f(v4.w);
  }
  float4 o; o.x = acc[0]; o.y = acc[1]; o.z = acc[2]; o.w = acc[3];
  *(float4*)&chunkAcc[((size_t)(b*NH + hh)*NCHUNK + c)*HDIM + ch0] = o;
}

// ---------------- scan pass 2: combine chunk carries sequentially ----------------
__global__ __launch_bounds__(64) void scan_pass2(
    const float* __restrict__ chunkAcc, float* __restrict__ carryPrev,
    const float* __restrict__ w)
{
  const int bh = blockIdx.x;
  const int h = bh & (NH-1);
  const int lanehd = threadIdx.x;
  const float e = expf(w[h*HDIM + lanehd]);
  const float dL = expf(-e * (float)CHUNKL);   // d^CHUNKL exactly
  const size_t base = (size_t)bh*NCHUNK*HDIM + lanehd;
  float carry = 0.f;
  for (int c = 0; c < NCHUNK; ++c) {
    carryPrev[base + (size_t)c*HDIM] = carry;  // acc entering chunk c
    carry = chunkAcc[base + (size_t)c*HDIM] + dL*carry;
  }
}

// ---------------- scan pass 3: recompute local scan + carry + u*kv + r* + LN + gate -> h(bf16) ----------------
__global__ __launch_bounds__(256) void scan_pass3(
    const u16* __restrict__ kbuf, const u16* __restrict__ vbuf,
    const u16* __restrict__ rbuf, const u16* __restrict__ gbuf,
    u16* __restrict__ hbuf, const float* __restrict__ carryPrev,
    const float* __restrict__ w, const float* __restrict__ u)
{
  const int c = blockIdx.x & (NCHUNK-1);
  const int b = blockIdx.x >> 7;
  const int hh = threadIdx.x >> 4;
  const int ch0 = (threadIdx.x & 15) << 2;
  const int hch = hh*HDIM + ch0;

  float dd[4], uv[4], carry[4], fac[4], acc[4];
#pragma unroll
  for (int j = 0; j < 4; ++j) {
    dd[j] = expf(-expf(w[hch + j]));
    uv[j] = u[hch + j];
    fac[j] = dd[j];
    acc[j] = 0.f;
  }
  const float4 cv = *(const float4*)&carryPrev[((size_t)(b*NH + hh)*NCHUNK + c)*HDIM + ch0];
  carry[0] = cv.x; carry[1] = cv.y; carry[2] = cv.z; carry[3] = cv.w;

  const size_t base = ((size_t)b*NSEQ + (size_t)c*CHUNKL)*DMODEL + hch;
#pragma unroll 4
  for (int i = 0; i < CHUNKL; ++i) {
    const size_t idx = base + (size_t)i*DMODEL;
    const ushort4 k4 = *(const ushort4*)(kbuf + idx);
    const ushort4 v4 = *(const ushort4*)(vbuf + idx);
    const ushort4 r4 = *(const ushort4*)(rbuf + idx);
    const ushort4 g4 = *(const ushort4*)(gbuf + idx);
    float rw[4];
    float s1 = 0.f, s2 = 0.f;
    {
      const float kv = b2f(k4.x)*b2f(v4.x);
      acc[0] = dd[0]*acc[0] + kv;
      const float wkv = acc[0] + fac[0]*carry[0] + uv[0]*kv;
      fac[0] *= dd[0];
      rw[0] = b2f(r4.x)*wkv; s1 += rw[0]; s2 += rw[0]*rw[0];
    }
    {
      const float kv = b2f(k4.y)*b2f(v4.y);
      acc[1] = dd[1]*acc[1] + kv;
      const float wkv = acc[1] + fac[1]*carry[1] + uv[1]*kv;
      fac[1] *= dd[1];
      rw[1] = b2f(r4.y)*wkv; s1 += rw[1]; s2 += rw[1]*rw[1];
    }
    {
      const float kv = b2f(k4.z)*b2f(v4.z);
      acc[2] = dd[2]*acc[2] + kv;
      const float wkv = acc[2] + fac[2]*carry[2] + uv[2]*kv;
      fac[2] *= dd[2];
      rw[2] = b2f(r4.z)*wkv; s1 += rw[2]; s2 += rw[2]*rw[2];
    }
    {
      const float kv = b2f(k4.w)*b2f(v4.w);
      acc[3] = dd[3]*acc[3] + kv;
      const float wkv = acc[3] + fac[3]*carry[3] + uv[3]*kv;
      fac[3] *= dd[3];
      rw[3] = b2f(r4.w)*wkv; s1 += rw[3]; s2 += rw[3]*rw[3];
    }
    // LN reduce over the 16-lane group (64 channels)
#pragma unroll
    for (int off = 8; off >= 1; off >>= 1) {
      s1 += __shfl_xor(s1, off);
      s2 += __shfl_xor(s2, off);
    }
    const float mean = s1 * (1.f/64.f);
    const float var = s2 * (1.f/64.f) - mean*mean;
    const float rstd = rsqrtf(var + 1e-5f);
    ushort4 o;
    o.x = f2b((rw[0]-mean)*rstd * (1.f/(1.f+expf(-b2f(g4.x)))));
    o.y = f2b((rw[1]-mean)*rstd * (1.f/(1.f+expf(-b2f(g4.y)))));
    o.z = f2b((rw[2]-mean)*rstd * (1.f/(1.f+expf(-b2f(g4.z)))));
    o.w = f2b((rw[3]-mean)*rstd * (1.f/(1.f+expf(-b2f(g4.w)))));
    *(ushort4*)(hbuf + idx) = o;
  }
}

// ---------------- launch ----------------
extern "C" void kernel_launch(void* const* d_in, const int* in_sizes, int n_in,
                              void* d_out, int out_size, void* d_ws, size_t ws_size,
                              hipStream_t stream)
{
  const float* x   = (const float*)d_in[0];
  const float* WgW = (const float*)d_in[1];
  const float* Wgb = (const float*)d_in[2];
  const float* WrW = (const float*)d_in[3];
  const float* Wrb = (const float*)d_in[4];
  const float* WkW = (const float*)d_in[5];
  const float* Wkb = (const float*)d_in[6];
  const float* WvW = (const float*)d_in[7];
  const float* Wvb = (const float*)d_in[8];
  const float* WoW = (const float*)d_in[9];
  const float* Wob = (const float*)d_in[10];
  const float* mg  = (const float*)d_in[11];
  const float* mr  = (const float*)d_in[12];
  const float* mk  = (const float*)d_in[13];
  const float* mv  = (const float*)d_in[14];
  const float* w   = (const float*)d_in[15];
  const float* u   = (const float*)d_in[16];
  char* ws = (char*)d_ws;

  const size_t WBB = (size_t)DMODEL*DMODEL*2;   // 2 MiB
  u16* WgB = (u16*)(ws + 0*WBB);
  u16* WrB = (u16*)(ws + 1*WBB);
  u16* WkB = (u16*)(ws + 2*WBB);
  u16* WvB = (u16*)(ws + 3*WBB);
  u16* WoB = (u16*)(ws + 4*WBB);
  size_t off = 5*WBB;
  const size_t EL = (size_t)MROWS*DMODEL;       // 33.5M elements

  // Am slots (4 x 64MiB bf16). Consumption order allows aliasing:
  //   kbuf -> Amg slot (free after g GEMM), vbuf -> Amr slot, hbuf -> Amk slot.
  char* amBase = ws + off;
  u16* Amg = (u16*)(amBase);
  u16* Amr = (u16*)(amBase + EL*2);
  u16* Amk = (u16*)(amBase + EL*4);
  u16* Amv = (u16*)(amBase + EL*6);
  u16* kbuf = Amg;
  u16* vbuf = Amr;
  u16* hbuf = Amk;
  off += EL*8;
  u16* gbuf = (u16*)(ws + off);   off += EL*2;
  u16* rbuf = (u16*)(ws + off);   off += EL*2;
  float* chunkAcc  = (float*)(ws + off); off += (size_t)NB*NH*NCHUNK*HDIM*4;
  float* carryPrev = (float*)(ws + off); off += (size_t)NB*NH*NCHUNK*HDIM*4;

  cvt5<<<640, 256, 0, stream>>>(WgW, WrW, WkW, WvW, WoW, WgB, WrB, WkB, WvB, WoB);

  mix4_kernel<<<(int)(EL/16/256), 256, 0, stream>>>(x, mg, mr, mk, mv, Amg, Amr, Amk, Amv);

  gemm256<1><<<512, 512, 0, stream>>>(Amg, WgB, Wgb, nullptr, gbuf);
  gemm256<1><<<512, 512, 0, stream>>>(Amr, WrB, Wrb, nullptr, rbuf);
  gemm256<1><<<512, 512, 0, stream>>>(Amk, WkB, Wkb, nullptr, kbuf);   // kbuf over consumed Amg
  gemm256<1><<<512, 512, 0, stream>>>(Amv, WvB, Wvb, nullptr, vbuf);   // vbuf over consumed Amr

  scan_pass1<<<NB*NCHUNK, 256, 0, stream>>>(kbuf, vbuf, w, chunkAcc);
  scan_pass2<<<NB*NH, 64, 0, stream>>>(chunkAcc, carryPrev, w);
  scan_pass3<<<NB*NCHUNK, 256, 0, stream>>>(kbuf, vbuf, rbuf, gbuf, hbuf, carryPrev, w, u);

  gemm256<0><<<512, 512, 0, stream>>>(hbuf, WoB, Wob, (float*)d_out, nullptr);
}

// Round 7
// 551.276 us; speedup vs baseline: 2.0617x; 1.0548x over previous
//
#include <hip/hip_runtime.h>
#include <stdint.h>

#define NB 8
#define NSEQ 4096
#define DMODEL 1024
#define NH 16
#define HDIM 64
#define MROWS (NB*NSEQ)      // 32768
#define NCHUNK 128
#define CHUNKL (NSEQ/NCHUNK) // 32
#define MIXROWS 16

typedef unsigned short u16;
typedef float f32x4 __attribute__((ext_vector_type(4)));
typedef short bf16x8 __attribute__((ext_vector_type(8)));

__device__ __forceinline__ u16 f2b(float f) {
  unsigned int u = __builtin_bit_cast(unsigned int, f);
  u = (u + 0x7FFFu + ((u >> 16) & 1u)) >> 16;
  return (u16)u;
}
__device__ __forceinline__ float b2f(u16 s) {
  unsigned int u = ((unsigned int)s) << 16;
  return __builtin_bit_cast(float, u);
}

// async global->LDS, 16B per lane (dest = wave-uniform base + lane*16)
__device__ __forceinline__ void gload16(const void* g, void* l) {
  __builtin_amdgcn_global_load_lds(
      (const __attribute__((address_space(1))) void*)g,
      (__attribute__((address_space(3))) void*)l, 16, 0, 0);
}

// ---------------- fused weight fp32 -> bf16 conversion (5 matrices) ----------------
__global__ __launch_bounds__(256) void cvt5(
    const float* __restrict__ a0, const float* __restrict__ a1,
    const float* __restrict__ a2, const float* __restrict__ a3,
    const float* __restrict__ a4,
    u16* __restrict__ b0, u16* __restrict__ b1, u16* __restrict__ b2,
    u16* __restrict__ b3, u16* __restrict__ b4)
{
  const int mat = blockIdx.x >> 7;    // 128 blocks per 1M-elem matrix
  const int blk = blockIdx.x & 127;
  const float* s; u16* d;
  switch (mat) {
    case 0: s = a0; d = b0; break;
    case 1: s = a1; d = b1; break;
    case 2: s = a2; d = b2; break;
    case 3: s = a3; d = b3; break;
    default: s = a4; d = b4; break;
  }
#pragma unroll
  for (int it = 0; it < 8; ++it) {
    const int idx = blk*8192 + it*1024 + threadIdx.x*4;
    const float4 v = *(const float4*)(s + idx);
    ushort4 o; o.x = f2b(v.x); o.y = f2b(v.y); o.z = f2b(v.z); o.w = f2b(v.w);
    *(ushort4*)(d + idx) = o;
  }
}

// ---------------- mix: fully-coalesced, x read once (register row-carry) ----------------
// 2048 blocks x 256 thr; block owns MIXROWS consecutive rows (never straddles a batch);
// thread t owns cols [4t, 4t+4). x_shift row = previous iteration's registers.
__global__ __launch_bounds__(256) void mix4_kernel(
    const float* __restrict__ X,
    const float* __restrict__ mg, const float* __restrict__ mr,
    const float* __restrict__ mk, const float* __restrict__ mv,
    u16* __restrict__ Ag, u16* __restrict__ Ar, u16* __restrict__ Ak, u16* __restrict__ Av)
{
  const int c4 = threadIdx.x * 4;
  const int r0 = blockIdx.x * MIXROWS;
  const float4 mgv = *(const float4*)(mg + c4);
  const float4 mrv = *(const float4*)(mr + c4);
  const float4 mkv = *(const float4*)(mk + c4);
  const float4 mvv = *(const float4*)(mv + c4);

  const int nidx = r0 & (NSEQ-1);
  const int prow = (nidx == 0) ? r0 + (NSEQ-1) : r0 - 1;
  float4 prev = *(const float4*)(X + (size_t)prow*DMODEL + c4);

#pragma unroll
  for (int j = 0; j < MIXROWS; ++j) {
    const size_t o = (size_t)(r0 + j)*DMODEL + c4;
    const float4 cur = *(const float4*)(X + o);
#define DO_MIX(MV, AP) { \
      ushort4 s_; \
      s_.x = f2b(MV.x*cur.x + (1.f-MV.x)*prev.x); \
      s_.y = f2b(MV.y*cur.y + (1.f-MV.y)*prev.y); \
      s_.z = f2b(MV.z*cur.z + (1.f-MV.z)*prev.z); \
      s_.w = f2b(MV.w*cur.w + (1.f-MV.w)*prev.w); \
      *(ushort4*)(AP + o) = s_; }
    DO_MIX(mgv, Ag)
    DO_MIX(mrv, Ar)
    DO_MIX(mkv, Ak)
    DO_MIX(mvv, Av)
#undef DO_MIX
    prev = cur;
  }
}

// ---------------- GEMM 256x256 8-phase (T1+T2+T3+T4+T5), C = A @ W^T + b ----------------
#define FENCE asm volatile("" ::: "memory")
#define BAR() { FENCE; __builtin_amdgcn_s_barrier(); FENCE; }
#define PRIO1 __builtin_amdgcn_s_setprio(1)
#define PRIO0 __builtin_amdgcn_s_setprio(0)
#define VM6 asm volatile("s_waitcnt vmcnt(6)" ::: "memory")
#define VM4 asm volatile("s_waitcnt vmcnt(4)" ::: "memory")
#define VM0 asm volatile("s_waitcnt vmcnt(0)" ::: "memory")

template<int OUTBF>
__global__ __launch_bounds__(512, 2) void gemm256(
    const u16* __restrict__ Abf, const u16* __restrict__ Wb,
    const float* __restrict__ bias, float* __restrict__ outF, u16* __restrict__ outB)
{
  __shared__ __align__(16) char lds[131072];
  const int tid = threadIdx.x;
  const int wave = tid >> 6, lane = tid & 63;
  const int wm = wave >> 2, wn = wave & 3;       // 2 x 4 waves
  const int rla = lane & 15, kgrp = lane >> 4;

  // T1: XCD-bijective swizzle. 512 blocks, xcd = wgid&7 owns by in [16*xcd, 16*xcd+16)
  const int wg = blockIdx.x;
  const int xcd = wg & 7, slot = wg >> 3;
  const int by = xcd*16 + (slot >> 2);
  const int bx = slot & 3;

  // staging source offsets (pre-swizzled): F = (wave*2+i)*1024 + lane*16
  const int F0 = (wave*2+0)*1024 + lane*16;
  const int F1 = (wave*2+1)*1024 + lane*16;
  const int r0 = F0 >> 6, r1 = F1 >> 6;
  const int c80 = ((F0 >> 4) & 3) ^ ((r0 >> 1) & 3);
  const int c81 = ((F1 >> 4) & 3) ^ ((r1 >> 1) & 3);
  const char* Ab = (const char*)Abf;
  const char* Bbp = (const char*)Wb;
  const unsigned ga0 = (unsigned)by*256*2048 + r0*2048 + c80*16;
  const unsigned ga1 = (unsigned)by*256*2048 + r1*2048 + c81*16;
  const unsigned gb0 = (unsigned)bx*256*2048 + r0*2048 + c80*16;
  const unsigned gb1 = (unsigned)bx*256*2048 + r1*2048 + c81*16;
  const int dst0 = wave*2048;
  const int dst1 = wave*2048 + 1024;

  f32x4 acc[8][4];
#pragma unroll
  for (int i = 0; i < 8; ++i)
#pragma unroll
    for (int j = 0; j < 4; ++j) acc[i][j] = f32x4{0.f,0.f,0.f,0.f};
  bf16x8 af[8], bfr[4];
  const int lane_ds = rla*64 + ((kgrp ^ ((rla>>1)&3)) << 4);

#define LDS_A(D,KK) (lds + (D)*32768 + (KK)*16384)
#define LDS_B(D,KK) (lds + 65536 + (D)*32768 + (KK)*16384)
#define LDA(D,KK) { _Pragma("unroll") for (int mi_ = 0; mi_ < 8; ++mi_) \
    af[mi_] = *(const bf16x8*)(LDS_A(D,KK) + (wm*128 + mi_*16)*64 + lane_ds); }
#define LDB(P,D,KK) { _Pragma("unroll") for (int j_ = 0; j_ < 2; ++j_) \
    bfr[(P)*2+j_] = *(const bf16x8*)(LDS_B(D,KK) + (wn*64 + ((P)*2+j_)*16)*64 + lane_ds); }
#define MM(P) { _Pragma("unroll") for (int mi_ = 0; mi_ < 8; ++mi_) { \
    acc[mi_][(P)*2+0] = __builtin_amdgcn_mfma_f32_16x16x32_bf16(af[mi_], bfr[(P)*2+0], acc[mi_][(P)*2+0], 0,0,0); \
    acc[mi_][(P)*2+1] = __builtin_amdgcn_mfma_f32_16x16x32_bf16(af[mi_], bfr[(P)*2+1], acc[mi_][(P)*2+1], 0,0,0); } }
#define STAGE(ISB, T, KK) { \
    const char* g_ = (ISB) ? Bbp : Ab; \
    const unsigned o0_ = ((ISB) ? gb0 : ga0) + (T)*128 + (KK)*64; \
    const unsigned o1_ = ((ISB) ? gb1 : ga1) + (T)*128 + (KK)*64; \
    char* l_ = (ISB) ? LDS_B((T)&1, KK) : LDS_A((T)&1, KK); \
    gload16(g_ + o0_, l_ + dst0); \
    gload16(g_ + o1_, l_ + dst1); }

  // prologue: tile0 all 4 halves, then tile1 A0,B0,A1
  STAGE(0, 0, 0); STAGE(1, 0, 0); STAGE(0, 0, 1); STAGE(1, 0, 1);
  VM4;
  STAGE(0, 1, 0); STAGE(1, 1, 0); STAGE(0, 1, 1);
  VM6;
  BAR();

  for (int i = 0; i < 8; ++i) {
    const int t1 = 2*i+1, t2 = 2*i+2, t3 = 2*i+3;
    const bool s2 = (i < 7);
    // ph1: compute tile 2i (buf0) kk0 ni01
    LDA(0,0); LDB(0,0,0); STAGE(1, t1, 1);
    BAR(); PRIO1; MM(0); PRIO0; BAR();
    // ph2: kk0 ni23
    LDB(1,0,0); if (s2) STAGE(0, t2, 0);
    BAR(); PRIO1; MM(1); PRIO0; BAR();
    // ph3: kk1 ni01
    LDA(0,1); LDB(0,0,1); if (s2) STAGE(1, t2, 0);
    BAR(); PRIO1; MM(0); PRIO0; BAR();
    // ph4: kk1 ni23  (+ counted vmcnt guarding tile 2i+1 reads)
    LDB(1,0,1); if (s2) STAGE(0, t2, 1);
    BAR(); PRIO1; MM(1); PRIO0;
    if (i == 7) { VM0; } else { VM6; }
    BAR();
    // ph5: tile 2i+1 (buf1) kk0 ni01
    LDA(1,0); LDB(0,1,0); if (s2) STAGE(1, t2, 1);
    BAR(); PRIO1; MM(0); PRIO0; BAR();
    // ph6
    LDB(1,1,0); if (s2) STAGE(0, t3, 0);
    BAR(); PRIO1; MM(1); PRIO0; BAR();
    // ph7
    LDA(1,1); LDB(0,1,1); if (s2) STAGE(1, t3, 0);
    BAR(); PRIO1; MM(0); PRIO0; BAR();
    // ph8  (+ counted vmcnt guarding next-iter tile reads)
    LDB(1,1,1); if (s2) STAGE(0, t3, 1);
    BAR(); PRIO1; MM(1); PRIO0; VM6; BAR();
  }

  // epilogue: bias + store. C/D: col=lane&15, row=(lane>>4)*4+q
  // loop order mi -> q -> ni so consecutive stores hit adjacent 32B halves of
  // the same 64B line (write-combine friendly; kills bf16 write amplification)
  float bval[4];
#pragma unroll
  for (int ni = 0; ni < 4; ++ni) bval[ni] = bias[bx*256 + wn*64 + ni*16 + rla];
#pragma unroll
  for (int mi = 0; mi < 8; ++mi) {
    const int gr0 = by*256 + wm*128 + mi*16 + kgrp*4;
    const int gcb = bx*256 + wn*64 + rla;
#pragma unroll
    for (int q = 0; q < 4; ++q) {
      const size_t rowo = (size_t)(gr0 + q)*DMODEL;
#pragma unroll
      for (int ni = 0; ni < 4; ++ni) {
        const float v = acc[mi][ni][q] + bval[ni];
        const size_t o = rowo + gcb + ni*16;
        if (OUTBF) outB[o] = f2b(v);
        else       outF[o] = v;
      }
    }
  }
#undef LDS_A
#undef LDS_B
#undef LDA
#undef LDB
#undef MM
#undef STAGE
}

// ---------------- scan pass 1: chunk-local carry compute only ----------------
// 1024 blocks = (b, chunk); 256 thr = 16 heads x 16 lanes, 4 ch/lane.
__global__ __launch_bounds__(256) void scan_pass1(
    const u16* __restrict__ kbuf, const u16* __restrict__ vbuf,
    const float* __restrict__ w, float* __restrict__ chunkAcc)
{
  const int c = blockIdx.x & (NCHUNK-1);
  const int b = blockIdx.x >> 7;            // NCHUNK=128
  const int hh = threadIdx.x >> 4;          // head 0..15
  const int ch0 = (threadIdx.x & 15) << 2;  // channel base 0..60
  const int hch = hh*HDIM + ch0;

  float dd[4];
#pragma unroll
  for (int j = 0; j < 4; ++j) dd[j] = expf(-expf(w[hch + j]));

  const size_t base = ((size_t)b*NSEQ + (size_t)c*CHUNKL)*DMODEL + hch;
  float acc[4] = {0.f, 0.f, 0.f, 0.f};
#pragma unroll 4
  for (int i = 0; i < CHUNKL; ++i) {
    const size_t idx = base + (size_t)i*DMODEL;
    const ushort4 k4 = *(const ushort4*)(kbuf + idx);
    const ushort4 v4 = *(const ushort4*)(vbuf + idx);
    acc[0] = dd[0]*acc[0] + b2f(k4.x)*b2f(v4.x);
    acc[1] = dd[1]*acc[1] + b2f(k4.y)*b2f(v4.y);
    acc[2] = dd[2]*acc[2] + b2f(k4.z)*b2f(v4.z);
    acc[3] = dd[3]*acc[3] + b2f(k4.w)*b2f(v4.w);
  }
  float4 o; o.x = acc[0]; o.y = acc[1]; o.z = acc[2]; o.w = acc[3];
  *(float4*)&chunkAcc[((size_t)(b*NH + hh)*NCHUNK + c)*HDIM + ch0] = o;
}

// ---------------- scan pass 2: combine chunk carries sequentially ----------------
__global__ __launch_bounds__(64) void scan_pass2(
    const float* __restrict__ chunkAcc, float* __restrict__ carryPrev,
    const float* __restrict__ w)
{
  const int bh = blockIdx.x;
  const int h = bh & (NH-1);
  const int lanehd = threadIdx.x;
  const float e = expf(w[h*HDIM + lanehd]);
  const float dL = expf(-e * (float)CHUNKL);   // d^CHUNKL exactly
  const size_t base = (size_t)bh*NCHUNK*HDIM + lanehd;
  float carry = 0.f;
  for (int c = 0; c < NCHUNK; ++c) {
    carryPrev[base + (size_t)c*HDIM] = carry;  // acc entering chunk c
    carry = chunkAcc[base + (size_t)c*HDIM] + dL*carry;
  }
}

// ---------------- scan pass 3: recompute local scan + carry + u*kv + r* + LN + gate -> h(bf16) ----------------
__global__ __launch_bounds__(256) void scan_pass3(
    const u16* __restrict__ kbuf, const u16* __restrict__ vbuf,
    const u16* __restrict__ rbuf, const u16* __restrict__ gbuf,
    u16* __restrict__ hbuf, const float* __restrict__ carryPrev,
    const float* __restrict__ w, const float* __restrict__ u)
{
  const int c = blockIdx.x & (NCHUNK-1);
  const int b = blockIdx.x >> 7;
  const int hh = threadIdx.x >> 4;
  const int ch0 = (threadIdx.x & 15) << 2;
  const int hch = hh*HDIM + ch0;

  float dd[4], uv[4], carry[4], fac[4], acc[4];
#pragma unroll
  for (int j = 0; j < 4; ++j) {
    dd[j] = expf(-expf(w[hch + j]));
    uv[j] = u[hch + j];
    fac[j] = dd[j];
    acc[j] = 0.f;
  }
  const float4 cv = *(const float4*)&carryPrev[((size_t)(b*NH + hh)*NCHUNK + c)*HDIM + ch0];
  carry[0] = cv.x; carry[1] = cv.y; carry[2] = cv.z; carry[3] = cv.w;

  const size_t base = ((size_t)b*NSEQ + (size_t)c*CHUNKL)*DMODEL + hch;
#pragma unroll 4
  for (int i = 0; i < CHUNKL; ++i) {
    const size_t idx = base + (size_t)i*DMODEL;
    const ushort4 k4 = *(const ushort4*)(kbuf + idx);
    const ushort4 v4 = *(const ushort4*)(vbuf + idx);
    const ushort4 r4 = *(const ushort4*)(rbuf + idx);
    const ushort4 g4 = *(const ushort4*)(gbuf + idx);
    float rw[4];
    float s1 = 0.f, s2 = 0.f;
    {
      const float kv = b2f(k4.x)*b2f(v4.x);
      acc[0] = dd[0]*acc[0] + kv;
      const float wkv = acc[0] + fac[0]*carry[0] + uv[0]*kv;
      fac[0] *= dd[0];
      rw[0] = b2f(r4.x)*wkv; s1 += rw[0]; s2 += rw[0]*rw[0];
    }
    {
      const float kv = b2f(k4.y)*b2f(v4.y);
      acc[1] = dd[1]*acc[1] + kv;
      const float wkv = acc[1] + fac[1]*carry[1] + uv[1]*kv;
      fac[1] *= dd[1];
      rw[1] = b2f(r4.y)*wkv; s1 += rw[1]; s2 += rw[1]*rw[1];
    }
    {
      const float kv = b2f(k4.z)*b2f(v4.z);
      acc[2] = dd[2]*acc[2] + kv;
      const float wkv = acc[2] + fac[2]*carry[2] + uv[2]*kv;
      fac[2] *= dd[2];
      rw[2] = b2f(r4.z)*wkv; s1 += rw[2]; s2 += rw[2]*rw[2];
    }
    {
      const float kv = b2f(k4.w)*b2f(v4.w);
      acc[3] = dd[3]*acc[3] + kv;
      const float wkv = acc[3] + fac[3]*carry[3] + uv[3]*kv;
      fac[3] *= dd[3];
      rw[3] = b2f(r4.w)*wkv; s1 += rw[3]; s2 += rw[3]*rw[3];
    }
    // LN reduce over the 16-lane group (64 channels)
#pragma unroll
    for (int off = 8; off >= 1; off >>= 1) {
      s1 += __shfl_xor(s1, off);
      s2 += __shfl_xor(s2, off);
    }
    const float mean = s1 * (1.f/64.f);
    const float var = s2 * (1.f/64.f) - mean*mean;
    const float rstd = rsqrtf(var + 1e-5f);
    ushort4 o;
    o.x = f2b((rw[0]-mean)*rstd * (1.f/(1.f+expf(-b2f(g4.x)))));
    o.y = f2b((rw[1]-mean)*rstd * (1.f/(1.f+expf(-b2f(g4.y)))));
    o.z = f2b((rw[2]-mean)*rstd * (1.f/(1.f+expf(-b2f(g4.z)))));
    o.w = f2b((rw[3]-mean)*rstd * (1.f/(1.f+expf(-b2f(g4.w)))));
    *(ushort4*)(hbuf + idx) = o;
  }
}

// ---------------- launch ----------------
extern "C" void kernel_launch(void* const* d_in, const int* in_sizes, int n_in,
                              void* d_out, int out_size, void* d_ws, size_t ws_size,
                              hipStream_t stream)
{
  const float* x   = (const float*)d_in[0];
  const float* WgW = (const float*)d_in[1];
  const float* Wgb = (const float*)d_in[2];
  const float* WrW = (const float*)d_in[3];
  const float* Wrb = (const float*)d_in[4];
  const float* WkW = (const float*)d_in[5];
  const float* Wkb = (const float*)d_in[6];
  const float* WvW = (const float*)d_in[7];
  const float* Wvb = (const float*)d_in[8];
  const float* WoW = (const float*)d_in[9];
  const float* Wob = (const float*)d_in[10];
  const float* mg  = (const float*)d_in[11];
  const float* mr  = (const float*)d_in[12];
  const float* mk  = (const float*)d_in[13];
  const float* mv  = (const float*)d_in[14];
  const float* w   = (const float*)d_in[15];
  const float* u   = (const float*)d_in[16];
  char* ws = (char*)d_ws;

  const size_t WBB = (size_t)DMODEL*DMODEL*2;   // 2 MiB
  u16* WgB = (u16*)(ws + 0*WBB);
  u16* WrB = (u16*)(ws + 1*WBB);
  u16* WkB = (u16*)(ws + 2*WBB);
  u16* WvB = (u16*)(ws + 3*WBB);
  u16* WoB = (u16*)(ws + 4*WBB);
  size_t off = 5*WBB;
  const size_t EL = (size_t)MROWS*DMODEL;       // 33.5M elements

  // Am slots (4 x 64MiB bf16). Consumption order allows aliasing:
  //   kbuf -> Amg slot (free after g GEMM), vbuf -> Amr slot, hbuf -> Amk slot.
  char* amBase = ws + off;
  u16* Amg = (u16*)(amBase);
  u16* Amr = (u16*)(amBase + EL*2);
  u16* Amk = (u16*)(amBase + EL*4);
  u16* Amv = (u16*)(amBase + EL*6);
  u16* kbuf = Amg;
  u16* vbuf = Amr;
  u16* hbuf = Amk;
  off += EL*8;
  u16* gbuf = (u16*)(ws + off);   off += EL*2;
  u16* rbuf = (u16*)(ws + off);   off += EL*2;
  float* chunkAcc  = (float*)(ws + off); off += (size_t)NB*NH*NCHUNK*HDIM*4;
  float* carryPrev = (float*)(ws + off); off += (size_t)NB*NH*NCHUNK*HDIM*4;

  cvt5<<<640, 256, 0, stream>>>(WgW, WrW, WkW, WvW, WoW, WgB, WrB, WkB, WvB, WoB);

  mix4_kernel<<<MROWS/MIXROWS, 256, 0, stream>>>(x, mg, mr, mk, mv, Amg, Amr, Amk, Amv);

  gemm256<1><<<512, 512, 0, stream>>>(Amg, WgB, Wgb, nullptr, gbuf);
  gemm256<1><<<512, 512, 0, stream>>>(Amr, WrB, Wrb, nullptr, rbuf);
  gemm256<1><<<512, 512, 0, stream>>>(Amk, WkB, Wkb, nullptr, kbuf);   // kbuf over consumed Amg
  gemm256<1><<<512, 512, 0, stream>>>(Amv, WvB, Wvb, nullptr, vbuf);   // vbuf over consumed Amr

  scan_pass1<<<NB*NCHUNK, 256, 0, stream>>>(kbuf, vbuf, w, chunkAcc);
  scan_pass2<<<NB*NH, 64, 0, stream>>>(chunkAcc, carryPrev, w);
  scan_pass3<<<NB*NCHUNK, 256, 0, stream>>>(kbuf, vbuf, rbuf, gbuf, hbuf, carryPrev, w, u);

  gemm256<0><<<512, 512, 0, stream>>>(hbuf, WoB, Wob, (float*)d_out, nullptr);
}

// Round 8
// 549.041 us; speedup vs baseline: 2.0701x; 1.0041x over previous
//
#include <hip/hip_runtime.h>
#include <stdint.h>

#define NB 8
#define NSEQ 4096
#define DMODEL 1024
#define NH 16
#define HDIM 64
#define MROWS (NB*NSEQ)      // 32768
#define NCHUNK 128
#define CHUNKL (NSEQ/NCHUNK) // 32
#define MIXROWS 16

typedef unsigned short u16;
typedef float f32x4 __attribute__((ext_vector_type(4)));
typedef short bf16x8 __attribute__((ext_vector_type(8)));

__device__ __forceinline__ u16 f2b(float f) {
  unsigned int u = __builtin_bit_cast(unsigned int, f);
  u = (u + 0x7FFFu + ((u >> 16) & 1u)) >> 16;
  return (u16)u;
}
__device__ __forceinline__ float b2f(u16 s) {
  unsigned int u = ((unsigned int)s) << 16;
  return __builtin_bit_cast(float, u);
}

// async global->LDS, 16B per lane (dest = wave-uniform base + lane*16)
__device__ __forceinline__ void gload16(const void* g, void* l) {
  __builtin_amdgcn_global_load_lds(
      (const __attribute__((address_space(1))) void*)g,
      (__attribute__((address_space(3))) void*)l, 16, 0, 0);
}

// ---------------- fused weight fp32 -> bf16 conversion (5 matrices) ----------------
__global__ __launch_bounds__(256) void cvt5(
    const float* __restrict__ a0, const float* __restrict__ a1,
    const float* __restrict__ a2, const float* __restrict__ a3,
    const float* __restrict__ a4,
    u16* __restrict__ b0, u16* __restrict__ b1, u16* __restrict__ b2,
    u16* __restrict__ b3, u16* __restrict__ b4)
{
  const int mat = blockIdx.x >> 7;    // 128 blocks per 1M-elem matrix
  const int blk = blockIdx.x & 127;
  const float* s; u16* d;
  switch (mat) {
    case 0: s = a0; d = b0; break;
    case 1: s = a1; d = b1; break;
    case 2: s = a2; d = b2; break;
    case 3: s = a3; d = b3; break;
    default: s = a4; d = b4; break;
  }
#pragma unroll
  for (int it = 0; it < 8; ++it) {
    const int idx = blk*8192 + it*1024 + threadIdx.x*4;
    const float4 v = *(const float4*)(s + idx);
    ushort4 o; o.x = f2b(v.x); o.y = f2b(v.y); o.z = f2b(v.z); o.w = f2b(v.w);
    *(ushort4*)(d + idx) = o;
  }
}

// ---------------- mix v4: 2 row-groups x 128 col-threads, 8 cols/thread ----------------
// 16B stores per matrix, x read once (register row-carry within group).
__global__ __launch_bounds__(256) void mix4_kernel(
    const float* __restrict__ X,
    const float* __restrict__ mg, const float* __restrict__ mr,
    const float* __restrict__ mk, const float* __restrict__ mv,
    u16* __restrict__ Ag, u16* __restrict__ Ar, u16* __restrict__ Ak, u16* __restrict__ Av)
{
  const int g = threadIdx.x >> 7;           // row-group 0/1
  const int t = threadIdx.x & 127;          // col-thread
  const int c8 = t * 8;
  const int r0 = blockIdx.x * MIXROWS + g * (MIXROWS/2);

  float mgv[8], mrv[8], mkv[8], mvv[8];
  *(float4*)&mgv[0] = *(const float4*)(mg + c8); *(float4*)&mgv[4] = *(const float4*)(mg + c8 + 4);
  *(float4*)&mrv[0] = *(const float4*)(mr + c8); *(float4*)&mrv[4] = *(const float4*)(mr + c8 + 4);
  *(float4*)&mkv[0] = *(const float4*)(mk + c8); *(float4*)&mkv[4] = *(const float4*)(mk + c8 + 4);
  *(float4*)&mvv[0] = *(const float4*)(mv + c8); *(float4*)&mvv[4] = *(const float4*)(mv + c8 + 4);

  const int nidx = r0 & (NSEQ-1);
  const int prow = (nidx == 0) ? r0 + (NSEQ-1) : r0 - 1;  // roll within batch
  float prev[8];
  *(float4*)&prev[0] = *(const float4*)(X + (size_t)prow*DMODEL + c8);
  *(float4*)&prev[4] = *(const float4*)(X + (size_t)prow*DMODEL + c8 + 4);

#pragma unroll
  for (int j = 0; j < MIXROWS/2; ++j) {
    const size_t o = (size_t)(r0 + j)*DMODEL + c8;
    float cur[8];
    *(float4*)&cur[0] = *(const float4*)(X + o);
    *(float4*)&cur[4] = *(const float4*)(X + o + 4);
#define DO_MIX(MV, AP) { \
      bf16x8 s_; \
      _Pragma("unroll") \
      for (int e = 0; e < 8; ++e) s_[e] = (short)f2b(prev[e] + MV[e]*(cur[e]-prev[e])); \
      *(bf16x8*)(AP + o) = s_; }
    DO_MIX(mgv, Ag)
    DO_MIX(mrv, Ar)
    DO_MIX(mkv, Ak)
    DO_MIX(mvv, Av)
#undef DO_MIX
#pragma unroll
    for (int e = 0; e < 8; ++e) prev[e] = cur[e];
  }
}

// ---------------- GEMM 256x256 8-phase (T1+T2+T3+T4+T5), C = A @ W^T + b ----------------
// NSEG=2: two independent GEMMs in one launch (seg = blockIdx.x>>9), disjoint buffers.
#define FENCE asm volatile("" ::: "memory")
#define BAR() { FENCE; __builtin_amdgcn_s_barrier(); FENCE; }
#define PRIO1 __builtin_amdgcn_s_setprio(1)
#define PRIO0 __builtin_amdgcn_s_setprio(0)
#define VM6 asm volatile("s_waitcnt vmcnt(6)" ::: "memory")
#define VM4 asm volatile("s_waitcnt vmcnt(4)" ::: "memory")
#define VM0 asm volatile("s_waitcnt vmcnt(0)" ::: "memory")

template<int OUTBF, int NSEG>
__global__ __launch_bounds__(512, 2) void gemm256(
    const u16* __restrict__ A0, const u16* __restrict__ W0,
    const float* __restrict__ b0, float* __restrict__ oF0, u16* __restrict__ oB0,
    const u16* __restrict__ A1, const u16* __restrict__ W1,
    const float* __restrict__ b1, float* __restrict__ oF1, u16* __restrict__ oB1)
{
  __shared__ __align__(16) char lds[131072];
  const int tid = threadIdx.x;
  const int wave = tid >> 6, lane = tid & 63;
  const int wm = wave >> 2, wn = wave & 3;       // 2 x 4 waves
  const int rla = lane & 15, kgrp = lane >> 4;

  const int seg = (NSEG == 2) ? (blockIdx.x >> 9) : 0;
  const u16* Abf = (seg == 0) ? A0 : A1;
  const u16* Wb  = (seg == 0) ? W0 : W1;
  const float* bias = (seg == 0) ? b0 : b1;
  float* outF = (seg == 0) ? oF0 : oF1;
  u16*   outB = (seg == 0) ? oB0 : oB1;

  // T1: XCD-bijective swizzle within each 512-block segment
  const int wg = blockIdx.x & 511;
  const int xcd = wg & 7, slot = wg >> 3;
  const int by = xcd*16 + (slot >> 2);
  const int bx = slot & 3;

  // staging source offsets (pre-swizzled): F = (wave*2+i)*1024 + lane*16
  const int F0 = (wave*2+0)*1024 + lane*16;
  const int F1 = (wave*2+1)*1024 + lane*16;
  const int r0 = F0 >> 6, r1 = F1 >> 6;
  const int c80 = ((F0 >> 4) & 3) ^ ((r0 >> 1) & 3);
  const int c81 = ((F1 >> 4) & 3) ^ ((r1 >> 1) & 3);
  const char* Ab = (const char*)Abf;
  const char* Bbp = (const char*)Wb;
  const unsigned ga0 = (unsigned)by*256*2048 + r0*2048 + c80*16;
  const unsigned ga1 = (unsigned)by*256*2048 + r1*2048 + c81*16;
  const unsigned gb0 = (unsigned)bx*256*2048 + r0*2048 + c80*16;
  const unsigned gb1 = (unsigned)bx*256*2048 + r1*2048 + c81*16;
  const int dst0 = wave*2048;
  const int dst1 = wave*2048 + 1024;

  f32x4 acc[8][4];
#pragma unroll
  for (int i = 0; i < 8; ++i)
#pragma unroll
    for (int j = 0; j < 4; ++j) acc[i][j] = f32x4{0.f,0.f,0.f,0.f};
  bf16x8 af[8], bfr[4];
  const int lane_ds = rla*64 + ((kgrp ^ ((rla>>1)&3)) << 4);

#define LDS_A(D,KK) (lds + (D)*32768 + (KK)*16384)
#define LDS_B(D,KK) (lds + 65536 + (D)*32768 + (KK)*16384)
#define LDA(D,KK) { _Pragma("unroll") for (int mi_ = 0; mi_ < 8; ++mi_) \
    af[mi_] = *(const bf16x8*)(LDS_A(D,KK) + (wm*128 + mi_*16)*64 + lane_ds); }
#define LDB(P,D,KK) { _Pragma("unroll") for (int j_ = 0; j_ < 2; ++j_) \
    bfr[(P)*2+j_] = *(const bf16x8*)(LDS_B(D,KK) + (wn*64 + ((P)*2+j_)*16)*64 + lane_ds); }
#define MM(P) { _Pragma("unroll") for (int mi_ = 0; mi_ < 8; ++mi_) { \
    acc[mi_][(P)*2+0] = __builtin_amdgcn_mfma_f32_16x16x32_bf16(af[mi_], bfr[(P)*2+0], acc[mi_][(P)*2+0], 0,0,0); \
    acc[mi_][(P)*2+1] = __builtin_amdgcn_mfma_f32_16x16x32_bf16(af[mi_], bfr[(P)*2+1], acc[mi_][(P)*2+1], 0,0,0); } }
#define STAGE(ISB, T, KK) { \
    const char* g_ = (ISB) ? Bbp : Ab; \
    const unsigned o0_ = ((ISB) ? gb0 : ga0) + (T)*128 + (KK)*64; \
    const unsigned o1_ = ((ISB) ? gb1 : ga1) + (T)*128 + (KK)*64; \
    char* l_ = (ISB) ? LDS_B((T)&1, KK) : LDS_A((T)&1, KK); \
    gload16(g_ + o0_, l_ + dst0); \
    gload16(g_ + o1_, l_ + dst1); }

  // prologue: tile0 all 4 halves, then tile1 A0,B0,A1
  STAGE(0, 0, 0); STAGE(1, 0, 0); STAGE(0, 0, 1); STAGE(1, 0, 1);
  VM4;
  STAGE(0, 1, 0); STAGE(1, 1, 0); STAGE(0, 1, 1);
  VM6;
  BAR();

  for (int i = 0; i < 8; ++i) {
    const int t1 = 2*i+1, t2 = 2*i+2, t3 = 2*i+3;
    const bool s2 = (i < 7);
    // ph1: compute tile 2i (buf0) kk0 ni01
    LDA(0,0); LDB(0,0,0); STAGE(1, t1, 1);
    BAR(); PRIO1; MM(0); PRIO0; BAR();
    // ph2: kk0 ni23
    LDB(1,0,0); if (s2) STAGE(0, t2, 0);
    BAR(); PRIO1; MM(1); PRIO0; BAR();
    // ph3: kk1 ni01
    LDA(0,1); LDB(0,0,1); if (s2) STAGE(1, t2, 0);
    BAR(); PRIO1; MM(0); PRIO0; BAR();
    // ph4: kk1 ni23  (+ counted vmcnt guarding tile 2i+1 reads)
    LDB(1,0,1); if (s2) STAGE(0, t2, 1);
    BAR(); PRIO1; MM(1); PRIO0;
    if (i == 7) { VM0; } else { VM6; }
    BAR();
    // ph5: tile 2i+1 (buf1) kk0 ni01
    LDA(1,0); LDB(0,1,0); if (s2) STAGE(1, t2, 1);
    BAR(); PRIO1; MM(0); PRIO0; BAR();
    // ph6
    LDB(1,1,0); if (s2) STAGE(0, t3, 0);
    BAR(); PRIO1; MM(1); PRIO0; BAR();
    // ph7
    LDA(1,1); LDB(0,1,1); if (s2) STAGE(1, t3, 0);
    BAR(); PRIO1; MM(0); PRIO0; BAR();
    // ph8  (+ counted vmcnt guarding next-iter tile reads)
    LDB(1,1,1); if (s2) STAGE(0, t3, 1);
    BAR(); PRIO1; MM(1); PRIO0; VM6; BAR();
  }

  // epilogue: bias + store. C/D: col=lane&15, row=(lane>>4)*4+q
  // loop order mi -> q -> ni: adjacent stores hit adjacent 32B halves of a 64B line
  float bval[4];
#pragma unroll
  for (int ni = 0; ni < 4; ++ni) bval[ni] = bias[bx*256 + wn*64 + ni*16 + rla];
#pragma unroll
  for (int mi = 0; mi < 8; ++mi) {
    const int gr0 = by*256 + wm*128 + mi*16 + kgrp*4;
    const int gcb = bx*256 + wn*64 + rla;
#pragma unroll
    for (int q = 0; q < 4; ++q) {
      const size_t rowo = (size_t)(gr0 + q)*DMODEL;
#pragma unroll
      for (int ni = 0; ni < 4; ++ni) {
        const float v = acc[mi][ni][q] + bval[ni];
        const size_t o = rowo + gcb + ni*16;
        if (OUTBF) outB[o] = f2b(v);
        else       outF[o] = v;
      }
    }
  }
#undef LDS_A
#undef LDS_B
#undef LDA
#undef LDB
#undef MM
#undef STAGE
}

// ---------------- scan pass 1: chunk-local carry compute only ----------------
__global__ __launch_bounds__(256) void scan_pass1(
    const u16* __restrict__ kbuf, const u16* __restrict__ vbuf,
    const float* __restrict__ w, float* __restrict__ chunkAcc)
{
  const int c = blockIdx.x & (NCHUNK-1);
  const int b = blockIdx.x >> 7;            // NCHUNK=128
  const int hh = threadIdx.x >> 4;          // head 0..15
  const int ch0 = (threadIdx.x & 15) << 2;  // channel base 0..60
  const int hch = hh*HDIM + ch0;

  float dd[4];
#pragma unroll
  for (int j = 0; j < 4; ++j) dd[j] = expf(-expf(w[hch + j]));

  const size_t base = ((size_t)b*NSEQ + (size_t)c*CHUNKL)*DMODEL + hch;
  float acc[4] = {0.f, 0.f, 0.f, 0.f};
#pragma unroll 4
  for (int i = 0; i < CHUNKL; ++i) {
    const size_t idx = base + (size_t)i*DMODEL;
    const ushort4 k4 = *(const ushort4*)(kbuf + idx);
    const ushort4 v4 = *(const ushort4*)(vbuf + idx);
    acc[0] = dd[0]*acc[0] + b2f(k4.x)*b2f(v4.x);
    acc[1] = dd[1]*acc[1] + b2f(k4.y)*b2f(v4.y);
    acc[2] = dd[2]*acc[2] + b2f(k4.z)*b2f(v4.z);
    acc[3] = dd[3]*acc[3] + b2f(k4.w)*b2f(v4.w);
  }
  float4 o; o.x = acc[0]; o.y = acc[1]; o.z = acc[2]; o.w = acc[3];
  *(float4*)&chunkAcc[((size_t)(b*NH + hh)*NCHUNK + c)*HDIM + ch0] = o;
}

// ---------------- scan pass 2: combine chunk carries sequentially ----------------
__global__ __launch_bounds__(64) void scan_pass2(
    const float* __restrict__ chunkAcc, float* __restrict__ carryPrev,
    const float* __restrict__ w)
{
  const int bh = blockIdx.x;
  const int h = bh & (NH-1);
  const int lanehd = threadIdx.x;
  const float e = expf(w[h*HDIM + lanehd]);
  const float dL = expf(-e * (float)CHUNKL);   // d^CHUNKL exactly
  const size_t base = (size_t)bh*NCHUNK*HDIM + lanehd;
  float carry = 0.f;
  for (int c = 0; c < NCHUNK; ++c) {
    carryPrev[base + (size_t)c*HDIM] = carry;  // acc entering chunk c
    carry = chunkAcc[base + (size_t)c*HDIM] + dL*carry;
  }
}

// ---------------- scan pass 3: recompute local scan + carry + u*kv + r* + LN + gate -> h(bf16) ----------------
__global__ __launch_bounds__(256) void scan_pass3(
    const u16* __restrict__ kbuf, const u16* __restrict__ vbuf,
    const u16* __restrict__ rbuf, const u16* __restrict__ gbuf,
    u16* __restrict__ hbuf, const float* __restrict__ carryPrev,
    const float* __restrict__ w, const float* __restrict__ u)
{
  const int c = blockIdx.x & (NCHUNK-1);
  const int b = blockIdx.x >> 7;
  const int hh = threadIdx.x >> 4;
  const int ch0 = (threadIdx.x & 15) << 2;
  const int hch = hh*HDIM + ch0;

  float dd[4], uv[4], carry[4], fac[4], acc[4];
#pragma unroll
  for (int j = 0; j < 4; ++j) {
    dd[j] = expf(-expf(w[hch + j]));
    uv[j] = u[hch + j];
    fac[j] = dd[j];
    acc[j] = 0.f;
  }
  const float4 cv = *(const float4*)&carryPrev[((size_t)(b*NH + hh)*NCHUNK + c)*HDIM + ch0];
  carry[0] = cv.x; carry[1] = cv.y; carry[2] = cv.z; carry[3] = cv.w;

  const size_t base = ((size_t)b*NSEQ + (size_t)c*CHUNKL)*DMODEL + hch;
#pragma unroll 4
  for (int i = 0; i < CHUNKL; ++i) {
    const size_t idx = base + (size_t)i*DMODEL;
    const ushort4 k4 = *(const ushort4*)(kbuf + idx);
    const ushort4 v4 = *(const ushort4*)(vbuf + idx);
    const ushort4 r4 = *(const ushort4*)(rbuf + idx);
    const ushort4 g4 = *(const ushort4*)(gbuf + idx);
    float rw[4];
    float s1 = 0.f, s2 = 0.f;
    {
      const float kv = b2f(k4.x)*b2f(v4.x);
      acc[0] = dd[0]*acc[0] + kv;
      const float wkv = acc[0] + fac[0]*carry[0] + uv[0]*kv;
      fac[0] *= dd[0];
      rw[0] = b2f(r4.x)*wkv; s1 += rw[0]; s2 += rw[0]*rw[0];
    }
    {
      const float kv = b2f(k4.y)*b2f(v4.y);
      acc[1] = dd[1]*acc[1] + kv;
      const float wkv = acc[1] + fac[1]*carry[1] + uv[1]*kv;
      fac[1] *= dd[1];
      rw[1] = b2f(r4.y)*wkv; s1 += rw[1]; s2 += rw[1]*rw[1];
    }
    {
      const float kv = b2f(k4.z)*b2f(v4.z);
      acc[2] = dd[2]*acc[2] + kv;
      const float wkv = acc[2] + fac[2]*carry[2] + uv[2]*kv;
      fac[2] *= dd[2];
      rw[2] = b2f(r4.z)*wkv; s1 += rw[2]; s2 += rw[2]*rw[2];
    }
    {
      const float kv = b2f(k4.w)*b2f(v4.w);
      acc[3] = dd[3]*acc[3] + kv;
      const float wkv = acc[3] + fac[3]*carry[3] + uv[3]*kv;
      fac[3] *= dd[3];
      rw[3] = b2f(r4.w)*wkv; s1 += rw[3]; s2 += rw[3]*rw[3];
    }
    // LN reduce over the 16-lane group (64 channels)
#pragma unroll
    for (int off = 8; off >= 1; off >>= 1) {
      s1 += __shfl_xor(s1, off);
      s2 += __shfl_xor(s2, off);
    }
    const float mean = s1 * (1.f/64.f);
    const float var = s2 * (1.f/64.f) - mean*mean;
    const float rstd = rsqrtf(var + 1e-5f);
    ushort4 o;
    o.x = f2b((rw[0]-mean)*rstd * (1.f/(1.f+expf(-b2f(g4.x)))));
    o.y = f2b((rw[1]-mean)*rstd * (1.f/(1.f+expf(-b2f(g4.y)))));
    o.z = f2b((rw[2]-mean)*rstd * (1.f/(1.f+expf(-b2f(g4.z)))));
    o.w = f2b((rw[3]-mean)*rstd * (1.f/(1.f+expf(-b2f(g4.w)))));
    *(ushort4*)(hbuf + idx) = o;
  }
}

// ---------------- launch ----------------
extern "C" void kernel_launch(void* const* d_in, const int* in_sizes, int n_in,
                              void* d_out, int out_size, void* d_ws, size_t ws_size,
                              hipStream_t stream)
{
  const float* x   = (const float*)d_in[0];
  const float* WgW = (const float*)d_in[1];
  const float* Wgb = (const float*)d_in[2];
  const float* WrW = (const float*)d_in[3];
  const float* Wrb = (const float*)d_in[4];
  const float* WkW = (const float*)d_in[5];
  const float* Wkb = (const float*)d_in[6];
  const float* WvW = (const float*)d_in[7];
  const float* Wvb = (const float*)d_in[8];
  const float* WoW = (const float*)d_in[9];
  const float* Wob = (const float*)d_in[10];
  const float* mg  = (const float*)d_in[11];
  const float* mr  = (const float*)d_in[12];
  const float* mk  = (const float*)d_in[13];
  const float* mv  = (const float*)d_in[14];
  const float* w   = (const float*)d_in[15];
  const float* u   = (const float*)d_in[16];
  char* ws = (char*)d_ws;

  const size_t WBB = (size_t)DMODEL*DMODEL*2;   // 2 MiB
  u16* WgB = (u16*)(ws + 0*WBB);
  u16* WrB = (u16*)(ws + 1*WBB);
  u16* WkB = (u16*)(ws + 2*WBB);
  u16* WvB = (u16*)(ws + 3*WBB);
  u16* WoB = (u16*)(ws + 4*WBB);
  size_t off = 5*WBB;
  const size_t EL = (size_t)MROWS*DMODEL;       // 33.5M elements

  // Am slots (4 x 64MiB bf16). Consumption order allows aliasing:
  //   kbuf -> Amg slot (k GEMM runs after g consumed Amg), vbuf -> Amr, hbuf -> Amk.
  char* amBase = ws + off;
  u16* Amg = (u16*)(amBase);
  u16* Amr = (u16*)(amBase + EL*2);
  u16* Amk = (u16*)(amBase + EL*4);
  u16* Amv = (u16*)(amBase + EL*6);
  u16* kbuf = Amg;
  u16* vbuf = Amr;
  u16* hbuf = Amk;
  off += EL*8;
  u16* gbuf = (u16*)(ws + off);   off += EL*2;
  u16* rbuf = (u16*)(ws + off);   off += EL*2;
  float* chunkAcc  = (float*)(ws + off); off += (size_t)NB*NH*NCHUNK*HDIM*4;
  float* carryPrev = (float*)(ws + off); off += (size_t)NB*NH*NCHUNK*HDIM*4;

  cvt5<<<640, 256, 0, stream>>>(WgW, WrW, WkW, WvW, WoW, WgB, WrB, WkB, WvB, WoB);

  mix4_kernel<<<MROWS/MIXROWS, 256, 0, stream>>>(x, mg, mr, mk, mv, Amg, Amr, Amk, Amv);

  // paired launches: {g,r} then {k,v} (disjoint buffers within each launch)
  gemm256<1,2><<<1024, 512, 0, stream>>>(Amg, WgB, Wgb, nullptr, gbuf,
                                         Amr, WrB, Wrb, nullptr, rbuf);
  gemm256<1,2><<<1024, 512, 0, stream>>>(Amk, WkB, Wkb, nullptr, kbuf,
                                         Amv, WvB, Wvb, nullptr, vbuf);

  scan_pass1<<<NB*NCHUNK, 256, 0, stream>>>(kbuf, vbuf, w, chunkAcc);
  scan_pass2<<<NB*NH, 64, 0, stream>>>(chunkAcc, carryPrev, w);
  scan_pass3<<<NB*NCHUNK, 256, 0, stream>>>(kbuf, vbuf, rbuf, gbuf, hbuf, carryPrev, w, u);

  gemm256<0,1><<<512, 512, 0, stream>>>(hbuf, WoB, Wob, (float*)d_out, nullptr,
                                        nullptr, nullptr, nullptr, nullptr, nullptr);
}